// Round 3
// baseline (588.794 us; speedup 1.0000x reference)
//
#include <hip/hip_runtime.h>
#include <math.h>

#define DIM 128
#define NEG_K 20

// Numerically stable log(sigmoid(x)) = min(x,0) - log1p(exp(-|x|))
__device__ __forceinline__ float log_sigmoid(float x) {
    float m = fminf(x, 0.0f);
    return m - log1pf(__expf(-fabsf(x)));
}

__device__ __forceinline__ float4 ld4(const float* p) { return *(const float4*)p; }
#define RFL(x) __builtin_amdgcn_readfirstlane(x)

// ONE WAVE per batch element. Row loads are paired: lanes 0-31 carry neg row
// 2j, lanes 32-63 carry neg row 2j+1 -> one global_load_dwordx4 per wave moves
// 1 KB (two full 512B rows). Indices are wave-uniform -> readfirstlane pins
// them in SGPRs (scalar addr math, ~half the VGPR pressure of the half-wave
// variant -> better occupancy to hide ~900cy HBM gather latency).
__global__ __launch_bounds__(256) void sgns_partial_kernel(
    const int* __restrict__ target,
    const int* __restrict__ context,
    const int* __restrict__ neg,
    const float* __restrict__ emb,
    float* __restrict__ partials,
    int B)
{
    const int tid  = blockIdx.x * blockDim.x + threadIdx.x;
    const int lane = threadIdx.x & 63;
    const int half = lane >> 5;          // 0: even rows / target, 1: odd / context
    const int sub  = lane & 31;          // float4 slot within the 512B row
    const int b    = tid >> 6;           // one wave per element

    float local = 0.0f;
    if (b < B) {
        const int tgt = RFL(target[b]);
        const int ctx = RFL(context[b]);
        const int4* __restrict__ nbv = (const int4*)(neg + (size_t)b * NEG_K);
        const int4 m0 = nbv[0], m1 = nbv[1], m2 = nbv[2], m3 = nbv[3], m4 = nbv[4];
        // even (k=0,2,..,18) for half 0, odd (k=1,3,..,19) for half 1
        const int ke[10] = { RFL(m0.x), RFL(m0.z), RFL(m1.x), RFL(m1.z), RFL(m2.x),
                             RFL(m2.z), RFL(m3.x), RFL(m3.z), RFL(m4.x), RFL(m4.z) };
        const int ko[10] = { RFL(m0.y), RFL(m0.w), RFL(m1.y), RFL(m1.w), RFL(m2.y),
                             RFL(m2.w), RFL(m3.y), RFL(m3.w), RFL(m4.y), RFL(m4.w) };

        const unsigned off = (unsigned)sub << 2;           // float offset in row
        const int r0 = half ? ctx : tgt;
        const float4 tv = ld4(emb + ((unsigned)r0 << 7) + off);

        float4 ns = make_float4(0.f, 0.f, 0.f, 0.f);
        #pragma unroll
        for (int j = 0; j < 10; ++j) {
            const int r = half ? ko[j] : ke[j];
            const float4 un = ld4(emb + ((unsigned)r << 7) + off);
            ns.x += un.x; ns.y += un.y; ns.z += un.z; ns.w += un.w;
        }

        // exchange target/context halves
        float4 ot;
        ot.x = __shfl_xor(tv.x, 32); ot.y = __shfl_xor(tv.y, 32);
        ot.z = __shfl_xor(tv.z, 32); ot.w = __shfl_xor(tv.w, 32);
        const float4 v4 = half ? ot : tv;                  // target row, both halves

        // p duplicated across halves (sum over 64 lanes = 2*pos);
        // g: each neg row counted once across the 64 lanes.
        float p = tv.x * ot.x + tv.y * ot.y + tv.z * ot.z + tv.w * ot.w;
        float g = ns.x * v4.x + ns.y * v4.y + ns.z * v4.z + ns.w * v4.w;
        #pragma unroll
        for (int o = 32; o; o >>= 1) {
            p += __shfl_xor(p, o);
            g += __shfl_xor(g, o);
        }
        if (lane == 0) local = log_sigmoid(0.5f * p) + log_sigmoid(-g);
    }

    __shared__ float wsum[4];
    if (lane == 0) wsum[threadIdx.x >> 6] = local;
    __syncthreads();
    if (threadIdx.x == 0)
        partials[blockIdx.x] = wsum[0] + wsum[1] + wsum[2] + wsum[3];
}

// Single-block reduction of per-block partials; writes the final loss.
__global__ __launch_bounds__(256) void sgns_reduce_kernel(
    const float* __restrict__ partials, float* __restrict__ out,
    int n, float invB)
{
    float s = 0.0f;
    for (int i = threadIdx.x; i < n; i += 256) s += partials[i];
    #pragma unroll
    for (int o = 32; o; o >>= 1) s += __shfl_xor(s, o);

    __shared__ float wsum[4];
    if ((threadIdx.x & 63) == 0) wsum[threadIdx.x >> 6] = s;
    __syncthreads();
    if (threadIdx.x == 0)
        out[0] = -(wsum[0] + wsum[1] + wsum[2] + wsum[3]) * invB;
}

extern "C" void kernel_launch(void* const* d_in, const int* in_sizes, int n_in,
                              void* d_out, int out_size, void* d_ws, size_t ws_size,
                              hipStream_t stream) {
    const int*   target  = (const int*)d_in[0];
    const int*   context = (const int*)d_in[1];
    const int*   neg     = (const int*)d_in[2];
    const float* emb     = (const float*)d_in[3];
    float* out      = (float*)d_out;
    float* partials = (float*)d_ws;
    const int B = in_sizes[0];

    const int threads = 256;
    const int blocks  = (B * 64 + threads - 1) / threads;   // one wave per b

    sgns_partial_kernel<<<blocks, threads, 0, stream>>>(target, context, neg,
                                                        emb, partials, B);
    sgns_reduce_kernel<<<1, threads, 0, stream>>>(partials, out, blocks,
                                                  1.0f / (float)B);
}